// Round 7
// baseline (293.950 us; speedup 1.0000x reference)
//
#include <hip/hip_runtime.h>
#include <hip/hip_bf16.h>
#include <math.h>

typedef short bf16x8 __attribute__((ext_vector_type(8)));
typedef float f32x4 __attribute__((ext_vector_type(4)));

static __device__ __forceinline__ unsigned short f2bf(float f) {
    unsigned int u = __float_as_uint(f);
    unsigned int r = (u + 0x7fffu + ((u >> 16) & 1u)) >> 16;
    return (unsigned short)r;
}

// elementwise square of a bf16x8 fragment (bf16 -> f32 -> square -> bf16 rne)
static __device__ __forceinline__ bf16x8 sq_bf16x8(bf16x8 a) {
    bf16x8 r;
    #pragma unroll
    for (int i = 0; i < 8; ++i) {
        unsigned int u = ((unsigned int)(unsigned short)a[i]) << 16;
        float f = __uint_as_float(u);
        f *= f;
        r[i] = (short)f2bf(f);
    }
    return r;
}

static __device__ __forceinline__ float gelu_f(float x) {
    return 0.5f * x * (1.f + erff(x * 0.70710678118654752f));
}

// async global->LDS, 16B per lane; LDS dest is wave-uniform base + lane*16
static __device__ __forceinline__ void gload_lds16(const void* g, void* l) {
    __builtin_amdgcn_global_load_lds(
        (const __attribute__((address_space(1))) unsigned int*)g,
        (__attribute__((address_space(3))) unsigned int*)l, 16, 0, 0);
}

// LDS index skew for FFT buffers
static __device__ __forceinline__ int ldsmap(int i) { return i + (i >> 6); }

static __device__ __forceinline__ int rev4(int k) {
    int d0 = k % 10; k /= 10;
    int d1 = k % 10; k /= 10;
    int d2 = k % 10; int d3 = k / 10;
    return d0 * 1000 + d1 * 100 + d2 * 10 + d3;
}

// forward 5-point DFT (W5 = e^{-2pi i/5}), Winograd-style
static __device__ __forceinline__ void dft5(
    float a0r, float a0i, float a1r, float a1i, float a2r, float a2i,
    float a3r, float a3i, float a4r, float a4i,
    float* Xr, float* Xi)
{
    const float c1 = 0.30901699437494742f, c2 = -0.80901699437494745f;
    const float s1 = 0.95105651629515357f, s2 = 0.58778525229247312f;
    float t1r = a1r + a4r, t1i = a1i + a4i;
    float d1r = a1r - a4r, d1i = a1i - a4i;
    float t2r = a2r + a3r, t2i = a2i + a3i;
    float d2r = a2r - a3r, d2i = a2i - a3i;
    Xr[0] = a0r + t1r + t2r; Xi[0] = a0i + t1i + t2i;
    float m1r = a0r + c1 * t1r + c2 * t2r, m1i = a0i + c1 * t1i + c2 * t2i;
    float m2r = a0r + c2 * t1r + c1 * t2r, m2i = a0i + c2 * t1i + c1 * t2i;
    float n1r = s1 * d1r + s2 * d2r, n1i = s1 * d1i + s2 * d2i;
    float n2r = s2 * d1r - s1 * d2r, n2i = s2 * d1i - s1 * d2i;
    Xr[1] = m1r + n1i; Xi[1] = m1i - n1r;
    Xr[4] = m1r - n1i; Xi[4] = m1i + n1r;
    Xr[2] = m2r + n2i; Xi[2] = m2i - n2r;
    Xr[3] = m2r - n2i; Xi[3] = m2i + n2r;
}

// One radix-10 DIF stage applied to TWO rows, sharing index math and the
// twiddle chain. w in [0,1000). S=0 fuses per-row mean subtract; S=3 has
// j=0 so twiddles are unity (skipped).
template<int S>
static __device__ __forceinline__ void radix10_stage2(
    float (*__restrict__ reb)[10156], float (*__restrict__ imb)[10156],
    int w, float mean0, float mean1)
{
    constexpr int L  = (S == 0) ? 1000 : (S == 1) ? 100 : (S == 2) ? 10 : 1;
    constexpr int SC = (S == 0) ? 1 : (S == 1) ? 10 : (S == 2) ? 100 : 1000;
    constexpr bool TW = (S != 3);

    const float WR[5] = {1.f, 0.80901699437494745f, 0.30901699437494742f,
                         -0.30901699437494742f, -0.80901699437494745f};
    const float WI[5] = {0.f, -0.58778525229247312f, -0.95105651629515357f,
                         -0.95105651629515357f, -0.58778525229247312f};

    int g, j;
    if (S == 0)      { g = 0; j = w; }
    else if (S == 3) { g = w; j = 0; }
    else             { g = w / L; j = w - g * L; }
    const int base = g * (10 * L) + j;

    // shared index set
    int idx[10];
    #pragma unroll
    for (int u = 0; u < 10; ++u) idx[u] = ldsmap(base + u * L);

    // shared twiddle chain
    float twr[10], twi[10];
    if (TW) {
        const float ang = (float)(j * SC) * -6.28318530717958648e-4f;
        float w1c, w1s;
        __sincosf(ang, &w1s, &w1c);
        twr[0] = 1.f; twi[0] = 0.f;
        #pragma unroll
        for (int t = 1; t < 10; ++t) {
            twr[t] = twr[t - 1] * w1c - twi[t - 1] * w1s;
            twi[t] = twr[t - 1] * w1s + twi[t - 1] * w1c;
        }
    }

    #pragma unroll
    for (int r = 0; r < 2; ++r) {
        const float mm = (S == 0) ? (r ? mean1 : mean0) : 0.f;
        float ar[10], ai[10];
        #pragma unroll
        for (int u = 0; u < 10; ++u) {
            ar[u] = reb[r][idx[u]] - mm;
            ai[u] = imb[r][idx[u]] - mm;
        }

        float Er[5], Ei[5], Or[5], Oi[5];
        dft5(ar[0], ai[0], ar[2], ai[2], ar[4], ai[4], ar[6], ai[6], ar[8], ai[8], Er, Ei);
        dft5(ar[1], ai[1], ar[3], ai[3], ar[5], ai[5], ar[7], ai[7], ar[9], ai[9], Or, Oi);
        #pragma unroll
        for (int k = 1; k < 5; ++k) {
            float tr = Or[k] * WR[k] - Oi[k] * WI[k];
            Oi[k] = Or[k] * WI[k] + Oi[k] * WR[k];
            Or[k] = tr;
        }

        if (TW) {
            #pragma unroll
            for (int k = 0; k < 5; ++k) {
                float xr0 = Er[k] + Or[k], xi0 = Ei[k] + Oi[k];
                float xr1 = Er[k] - Or[k], xi1 = Ei[k] - Oi[k];
                if (k == 0) {
                    reb[r][idx[0]] = xr0;
                    imb[r][idx[0]] = xi0;
                } else {
                    reb[r][idx[k]] = xr0 * twr[k] - xi0 * twi[k];
                    imb[r][idx[k]] = xr0 * twi[k] + xi0 * twr[k];
                }
                reb[r][idx[k + 5]] = xr1 * twr[k + 5] - xi1 * twi[k + 5];
                imb[r][idx[k + 5]] = xr1 * twi[k + 5] + xi1 * twr[k + 5];
            }
        } else {
            #pragma unroll
            for (int k = 0; k < 5; ++k) {
                reb[r][idx[k]]     = Er[k] + Or[k]; imb[r][idx[k]]     = Ei[k] + Oi[k];
                reb[r][idx[k + 5]] = Er[k] - Or[k]; imb[r][idx[k + 5]] = Ei[k] - Oi[k];
            }
        }
    }
}

// ---------------------------------------------------------------------------
// Fused FFT + prep. Blocks [0,512): TWO FFT rows per block (1024 threads,
// 158.8 KB LDS, 1 block/CU = 16 waves) — twiddle chain, LDS index math,
// rev4 and untangle sincos computed once and applied to both rows.
// Blocks [512, 1902): weight prep.
// ---------------------------------------------------------------------------
__global__ __launch_bounds__(1024)
void fft_prep_kernel(const float* __restrict__ x,
                     unsigned short* __restrict__ hb,
                     float* __restrict__ hnorm,
                     const float* __restrict__ W0, const float* __restrict__ A0,
                     unsigned short* __restrict__ Wb, unsigned short* __restrict__ Sb,
                     const float* __restrict__ W1, const float* __restrict__ A1,
                     const float* __restrict__ W2, const float* __restrict__ A2,
                     float* __restrict__ W1T, float* __restrict__ S1T,
                     float* __restrict__ W2T, float* __restrict__ S2T)
{
    if (blockIdx.x >= 512) {
        // ---- prep path ----
        int idx = (blockIdx.x - 512) * 1024 + threadIdx.x;
        if (idx < 1280128) {
            const bool isW = idx < 640064;
            const int f4 = isW ? idx : idx - 640064;
            const float* src = isW ? W0 : A0;
            unsigned short* dst = isW ? Wb : Sb;
            float4 v = ((const float4*)src)[f4];
            float e[4] = {v.x, v.y, v.z, v.w};
            int flat = f4 * 4;
            int row = flat / 10001;
            int col = flat - row * 10001;
            #pragma unroll
            for (int i = 0; i < 4; ++i) {
                if (col == 10001) { row++; col = 0; }
                float val = isW ? e[i] : 1.f / (1.f + expf(-e[i]));
                dst[(size_t)row * 10240 + col] = f2bf(val);
                col++;
            }
        } else if (idx < 1341312) {
            int i = idx - 1280128;              // 256*239 pads
            int row = i / 239;
            int col = 10001 + (i - row * 239);
            Wb[(size_t)row * 10240 + col] = 0;
            Sb[(size_t)row * 10240 + col] = 0;
        } else if (idx < 1423232) {
            int o = idx - 1341312;              // 0..81919
            if (o < 32768) {
                int d = o >> 7, h = o & 127;
                W1T[o] = W1[h * 256 + d];
            } else if (o < 65536) {
                int p = o - 32768;
                int d = p >> 7, h = p & 127;
                S1T[p] = 1.f / (1.f + expf(-A1[h * 256 + d]));
            } else if (o < 73728) {
                int p = o - 65536;
                int d = p >> 6, h = p & 63;
                W2T[p] = W2[h * 128 + d];
            } else {
                int p = o - 73728;
                int d = p >> 6, h = p & 63;
                S2T[p] = 1.f / (1.f + expf(-A2[h * 128 + d]));
            }
        }
        return;
    }

    // ---- FFT path: rows b0 and b0+1 ----
    __shared__ float reb[2][10156];
    __shared__ float imb[2][10156];
    __shared__ float redbuf[32];

    const int tid = threadIdx.x;        // 0..1023
    const int lane = tid & 63;
    const int wv = tid >> 6;            // 0..15
    const int half = tid >> 9;          // 0 or 1: which row this thread packs
    const int t2 = tid & 511;
    const int b0 = blockIdx.x * 2;

    // pack: half-block per row, vectorized float4, accumulate row sum
    const float* xr = x + (size_t)(b0 + half) * 20000;
    float sum = 0.f;
    for (int i4 = t2; i4 < 5000; i4 += 512) {
        float4 v = ((const float4*)xr)[i4];
        sum += v.x + v.y + v.z + v.w;
        int n = i4 * 2;
        reb[half][ldsmap(n)]     = v.x; imb[half][ldsmap(n)]     = v.y;
        reb[half][ldsmap(n + 1)] = v.z; imb[half][ldsmap(n + 1)] = v.w;
    }
    #pragma unroll
    for (int o = 32; o; o >>= 1) sum += __shfl_xor(sum, o);
    __syncthreads();                 // pack complete
    if (lane == 0) redbuf[wv] = sum; // waves 0..7 -> row0, 8..15 -> row1
    __syncthreads();
    float tot0 = 0.f, tot1 = 0.f;
    #pragma unroll
    for (int i = 0; i < 8; ++i) { tot0 += redbuf[i]; tot1 += redbuf[8 + i]; }
    const float mean0 = tot0 * (1.f / 20000.f);
    const float mean1 = tot1 * (1.f / 20000.f);

    if (tid < 1000) radix10_stage2<0>(reb, imb, tid, mean0, mean1);
    __syncthreads();
    if (tid < 1000) radix10_stage2<1>(reb, imb, tid, 0.f, 0.f);
    __syncthreads();
    if (tid < 1000) radix10_stage2<2>(reb, imb, tid, 0.f, 0.f);
    __syncthreads();
    if (tid < 1000) radix10_stage2<3>(reb, imb, tid, 0.f, 0.f);
    __syncthreads();

    // real-FFT untangle + log1p|X| for both rows; index math + sincos shared
    float sq0 = 0.f, sq1 = 0.f;
    unsigned short* hrow0 = hb + (size_t)b0 * 10240;
    unsigned short* hrow1 = hrow0 + 10240;
    #pragma unroll
    for (int i = 0; i < 10; ++i) {
        int k = tid + i * 1024;          // 0..10239
        if (k <= 10000) {
            int k1 = (k == 10000) ? 0 : k;
            int k2 = (10000 - k1) % 10000;
            int i1 = ldsmap(rev4(k1));
            int i2 = ldsmap(rev4(k2));
            float ct, st;
            __sincosf((float)k * -3.14159265358979324e-4f, &st, &ct);

            {   // row 0
                float zr = reb[0][i1], zi = imb[0][i1];
                float wr = reb[0][i2], wi = imb[0][i2];
                float er = 0.5f * (zr + wr);
                float ei = 0.5f * (zi - wi);
                float odr = 0.5f * (zi + wi);
                float odi = -0.5f * (zr - wr);
                float xre = er + ct * odr - st * odi;
                float xim = ei + ct * odi + st * odr;
                float hv = log1pf(sqrtf(xre * xre + xim * xim));
                hrow0[k] = f2bf(hv);
                sq0 += hv * hv;
            }
            {   // row 1
                float zr = reb[1][i1], zi = imb[1][i1];
                float wr = reb[1][i2], wi = imb[1][i2];
                float er = 0.5f * (zr + wr);
                float ei = 0.5f * (zi - wi);
                float odr = 0.5f * (zi + wi);
                float odi = -0.5f * (zr - wr);
                float xre = er + ct * odr - st * odi;
                float xim = ei + ct * odi + st * odr;
                float hv = log1pf(sqrtf(xre * xre + xim * xim));
                hrow1[k] = f2bf(hv);
                sq1 += hv * hv;
            }
        } else {
            hrow0[k] = 0;               // K-pad
            hrow1[k] = 0;
        }
    }
    #pragma unroll
    for (int o = 32; o; o >>= 1) { sq0 += __shfl_xor(sq0, o); sq1 += __shfl_xor(sq1, o); }
    __syncthreads();
    if (lane == 0) { redbuf[wv] = sq0; redbuf[16 + wv] = sq1; }
    __syncthreads();
    if (tid == 0) {
        float t = 0.f;
        #pragma unroll
        for (int i = 0; i < 16; ++i) t += redbuf[i];
        hnorm[b0] = 1.f / (sqrtf(t) + 1e-8f);
    } else if (tid == 1) {
        float t = 0.f;
        #pragma unroll
        for (int i = 0; i < 16; ++i) t += redbuf[16 + i];
        hnorm[b0 + 1] = 1.f / (sqrtf(t) + 1e-8f);
    }
}

// ---------------------------------------------------------------------------
// Layer-0 dual GEMM: Y = h*W0^T, P = (h^2)*S0^T (1/||h|| applied in combine).
// BM=128 BN=64 BK=64, split-K=16. grid (8,4,16) x 256. LDS 32 KB.
// ---------------------------------------------------------------------------
__global__ __launch_bounds__(256, 2)
void gemm0_kernel(const unsigned short* __restrict__ hb,
                  const unsigned short* __restrict__ Wb, const unsigned short* __restrict__ Sb,
                  float* __restrict__ Py, float* __restrict__ Pp)
{
    __shared__ unsigned short Ah[128 * 64];
    __shared__ unsigned short Bw[64 * 64];
    __shared__ unsigned short Bs[64 * 64];

    const int t = threadIdx.x;
    const int b0 = blockIdx.x * 128;
    const int n0 = blockIdx.y * 64;
    const int z = blockIdx.z;
    const int lane = t & 63;
    const int wv = t >> 6;
    const int ml = lane & 15;
    const int q4 = lane >> 4;
    const int s0 = q4 ^ (ml & 7);

    const int sub = lane >> 3;
    const int sl = lane & 7;
    const int gsw = sl ^ sub;

    f32x4 accY[2][4], accP[2][4];
    #pragma unroll
    for (int mt = 0; mt < 2; ++mt)
        #pragma unroll
        for (int nt = 0; nt < 4; ++nt) {
            accY[mt][nt] = (f32x4){0.f, 0.f, 0.f, 0.f};
            accP[mt][nt] = (f32x4){0.f, 0.f, 0.f, 0.f};
        }

    const int kbase = z * 640;

    for (int step = 0; step < 10; ++step) {
        const int k0 = kbase + step * 64;
        __syncthreads();
        #pragma unroll
        for (int j = 0; j < 4; ++j) {
            const int c = wv * 4 + j;
            const size_t go = (size_t)(b0 + c * 8 + sub) * 10240 + k0 + gsw * 8;
            gload_lds16(&hb[go], &Ah[c * 512]);
        }
        #pragma unroll
        for (int j = 0; j < 2; ++j) {
            const int c = wv * 2 + j;
            const size_t go = (size_t)(n0 + c * 8 + sub) * 10240 + k0 + gsw * 8;
            gload_lds16(&Wb[go], &Bw[c * 512]);
            gload_lds16(&Sb[go], &Bs[c * 512]);
        }
        __syncthreads();

        #pragma unroll
        for (int kk = 0; kk < 2; ++kk) {
            const int slot = (s0 ^ (kk << 2)) << 3;
            bf16x8 ah[2], ac[2], bw[4], bs[4];
            #pragma unroll
            for (int mt = 0; mt < 2; ++mt) {
                int mrow = wv * 32 + mt * 16 + ml;
                ah[mt] = *(const bf16x8*)&Ah[mrow * 64 + slot];
                ac[mt] = sq_bf16x8(ah[mt]);
            }
            #pragma unroll
            for (int nt = 0; nt < 4; ++nt) {
                int nrow = nt * 16 + ml;
                bw[nt] = *(const bf16x8*)&Bw[nrow * 64 + slot];
                bs[nt] = *(const bf16x8*)&Bs[nrow * 64 + slot];
            }
            #pragma unroll
            for (int mt = 0; mt < 2; ++mt)
                #pragma unroll
                for (int nt = 0; nt < 4; ++nt) {
                    accY[mt][nt] = __builtin_amdgcn_mfma_f32_16x16x32_bf16(ah[mt], bw[nt], accY[mt][nt], 0, 0, 0);
                    accP[mt][nt] = __builtin_amdgcn_mfma_f32_16x16x32_bf16(ac[mt], bs[nt], accP[mt][nt], 0, 0, 0);
                }
        }
    }

    const int rq = q4 * 4;
    #pragma unroll
    for (int mt = 0; mt < 2; ++mt)
        #pragma unroll
        for (int nt = 0; nt < 4; ++nt)
            #pragma unroll
            for (int r = 0; r < 4; ++r) {
                int m = b0 + wv * 32 + mt * 16 + rq + r;
                int n = n0 + nt * 16 + ml;
                size_t o = ((size_t)z * 1024 + m) * 256 + n;
                Py[o] = accY[mt][nt][r];
                Pp[o] = accP[mt][nt][r];
            }
}

// ---------------------------------------------------------------------------
// Combine splits + bias + plastic (x inv norm) + LayerNorm(256) + GELU + c1.
// ---------------------------------------------------------------------------
__global__ __launch_bounds__(256)
void combine0_kernel(const float* __restrict__ Py, const float* __restrict__ Pp,
                     const float* __restrict__ hnorm,
                     const float* __restrict__ b0v, const float* __restrict__ eta0p,
                     const float* __restrict__ g0, const float* __restrict__ be0,
                     float* __restrict__ h1, float* __restrict__ c1)
{
    __shared__ float red[4];
    const int b = blockIdx.x;
    const int h = threadIdx.x;
    const int lane = h & 63;
    const int wv = h >> 6;

    float ys = 0.f, ps = 0.f;
    for (int s = 0; s < 16; ++s) {
        size_t o = ((size_t)s * 1024 + b) * 256 + h;
        ys += Py[o];
        ps += Pp[o];
    }
    ps *= hnorm[b];                      // fold in 1/(||h||+1e-8)
    float y = ys + b0v[h];
    float v = y + eta0p[0] * tanhf(y) * ps;

    float s1 = v;
    #pragma unroll
    for (int o = 32; o; o >>= 1) s1 += __shfl_xor(s1, o);
    __syncthreads();
    if (lane == 0) red[wv] = s1;
    __syncthreads();
    float sum = red[0] + red[1] + red[2] + red[3];

    float s2 = v * v;
    #pragma unroll
    for (int o = 32; o; o >>= 1) s2 += __shfl_xor(s2, o);
    __syncthreads();
    if (lane == 0) red[wv] = s2;
    __syncthreads();
    float sumsq = red[0] + red[1] + red[2] + red[3];

    float mu = sum * (1.f / 256.f);
    float var = sumsq * (1.f / 256.f) - mu * mu;
    float u = (v - mu) * rsqrtf(var + 1e-5f) * g0[h] + be0[h];
    float gl = gelu_f(u);

    float s3 = gl * gl;
    #pragma unroll
    for (int o = 32; o; o >>= 1) s3 += __shfl_xor(s3, o);
    __syncthreads();
    if (lane == 0) red[wv] = s3;
    __syncthreads();
    float gsq = red[0] + red[1] + red[2] + red[3];
    float inv = 1.f / (sqrtf(gsq) + 1e-8f);

    h1[(size_t)b * 256 + h] = gl;
    c1[(size_t)b * 256 + h] = gl * gl * inv;
}

// ---------------------------------------------------------------------------
// Tail: layers 1,2 + head, fp32. 4 rows per block. grid 256, block 256.
// ---------------------------------------------------------------------------
__global__ __launch_bounds__(256)
void tail_kernel(const float* __restrict__ h1, const float* __restrict__ c1,
                 const float* __restrict__ W1T, const float* __restrict__ S1T,
                 const float* __restrict__ b1, const float* __restrict__ eta1p,
                 const float* __restrict__ g1, const float* __restrict__ be1,
                 const float* __restrict__ W2T, const float* __restrict__ S2T,
                 const float* __restrict__ b2, const float* __restrict__ eta2p,
                 const float* __restrict__ g2, const float* __restrict__ be2,
                 const float* __restrict__ hw, const float* __restrict__ hbod,
                 float* __restrict__ out)
{
    __shared__ float sh[4][256];
    __shared__ float sc[4][256];
    __shared__ float sv[4][128];
    __shared__ float sh2[4][128];
    __shared__ float sc2[4][128];
    __shared__ float sv2[4][64];

    const int t = threadIdx.x;
    const int b0 = blockIdx.x * 4;
    const int lane = t & 63;
    const int wv = t >> 6;

    #pragma unroll
    for (int i = 0; i < 4; ++i) {
        int idx = t + i * 256;
        int r = idx >> 8, d = idx & 255;
        sh[r][d] = h1[(size_t)(b0 + r) * 256 + d];
        sc[r][d] = c1[(size_t)(b0 + r) * 256 + d];
    }
    __syncthreads();

    // layer 1: 128 outputs x 4 rows; each thread 2 rows
    const int hcol = t & 127;
    const int r2 = t >> 7;           // 0..1
    float ya[2] = {0.f, 0.f};
    float pa[2] = {0.f, 0.f};
    for (int d = 0; d < 256; ++d) {
        float w = W1T[d * 128 + hcol];
        float s = S1T[d * 128 + hcol];
        #pragma unroll
        for (int i = 0; i < 2; ++i) {
            int r = r2 * 2 + i;
            ya[i] += sh[r][d] * w;
            pa[i] += sc[r][d] * s;
        }
    }
    const float e1 = eta1p[0];
    #pragma unroll
    for (int i = 0; i < 2; ++i) {
        int r = r2 * 2 + i;
        float y = ya[i] + b1[hcol];
        sv[r][hcol] = y + e1 * tanhf(y) * pa[i];
    }
    __syncthreads();

    // LN(128) + gelu + c2: wave per row
    {
        int r = wv;
        float v0 = sv[r][lane];
        float v1 = sv[r][lane + 64];
        float s = v0 + v1, sq = v0 * v0 + v1 * v1;
        #pragma unroll
        for (int o = 32; o; o >>= 1) { s += __shfl_xor(s, o); sq += __shfl_xor(sq, o); }
        float mu = s * (1.f / 128.f);
        float var = sq * (1.f / 128.f) - mu * mu;
        float rs = rsqrtf(var + 1e-5f);
        float u0 = (v0 - mu) * rs * g1[lane] + be1[lane];
        float u1 = (v1 - mu) * rs * g1[lane + 64] + be1[lane + 64];
        float ge0 = gelu_f(u0);
        float ge1 = gelu_f(u1);
        float gsq = ge0 * ge0 + ge1 * ge1;
        #pragma unroll
        for (int o = 32; o; o >>= 1) gsq += __shfl_xor(gsq, o);
        float inv = 1.f / (sqrtf(gsq) + 1e-8f);
        sh2[r][lane] = ge0; sh2[r][lane + 64] = ge1;
        sc2[r][lane] = ge0 * ge0 * inv; sc2[r][lane + 64] = ge1 * ge1 * inv;
    }
    __syncthreads();

    // layer 2: 64 outputs x 4 rows; one item per thread
    const int h2c = t & 63;
    const int r4 = t >> 6;           // 0..3
    float yb = 0.f, pb = 0.f;
    for (int d = 0; d < 128; ++d) {
        yb += sh2[r4][d] * W2T[d * 64 + h2c];
        pb += sc2[r4][d] * S2T[d * 64 + h2c];
    }
    {
        const float e2 = eta2p[0];
        float y = yb + b2[h2c];
        sv2[r4][h2c] = y + e2 * tanhf(y) * pb;
    }
    __syncthreads();

    // LN(64) + gelu + head: wave per row
    {
        int r = wv;
        float v0 = sv2[r][lane];
        float s = v0, sq = v0 * v0;
        #pragma unroll
        for (int o = 32; o; o >>= 1) { s += __shfl_xor(s, o); sq += __shfl_xor(sq, o); }
        float mu = s * (1.f / 64.f);
        float var = sq * (1.f / 64.f) - mu * mu;
        float rs = rsqrtf(var + 1e-5f);
        float u = (v0 - mu) * rs * g2[lane] + be2[lane];
        float g = gelu_f(u);
        float hc = g * hw[lane];
        #pragma unroll
        for (int o = 32; o; o >>= 1) hc += __shfl_xor(hc, o);
        if (lane == 0) out[b0 + r] = hc + hbod[0];
    }
}

// ---------------------------------------------------------------------------
extern "C" void kernel_launch(void* const* d_in, const int* in_sizes, int n_in,
                              void* d_out, int out_size, void* d_ws, size_t ws_size,
                              hipStream_t stream)
{
    const float* x    = (const float*)d_in[0];
    const float* W0   = (const float*)d_in[1];
    const float* A0   = (const float*)d_in[2];
    const float* b0   = (const float*)d_in[3];
    const float* eta0 = (const float*)d_in[4];
    const float* g0   = (const float*)d_in[5];
    const float* be0  = (const float*)d_in[6];
    const float* W1   = (const float*)d_in[7];
    const float* A1   = (const float*)d_in[8];
    const float* b1   = (const float*)d_in[9];
    const float* eta1 = (const float*)d_in[10];
    const float* g1   = (const float*)d_in[11];
    const float* be1  = (const float*)d_in[12];
    const float* W2   = (const float*)d_in[13];
    const float* A2   = (const float*)d_in[14];
    const float* b2   = (const float*)d_in[15];
    const float* eta2 = (const float*)d_in[16];
    const float* g2   = (const float*)d_in[17];
    const float* be2  = (const float*)d_in[18];
    const float* hw   = (const float*)d_in[19];
    const float* hbod = (const float*)d_in[20];
    float* out = (float*)d_out;

    char* w = (char*)d_ws;
    unsigned short* hb  = (unsigned short*)(w + 0);          // 20971520
    unsigned short* Wb0 = (unsigned short*)(w + 20971520);   // 5242880
    unsigned short* Sb0 = (unsigned short*)(w + 26214400);   // 5242880
    float* Py   = (float*)(w + 31457280);                    // 16777216
    float* Pp   = (float*)(w + 48234496);                    // 16777216
    float* h1   = (float*)(w + 65011712);                    // 1048576
    float* c1   = (float*)(w + 66060288);                    // 1048576
    float* W1T  = (float*)(w + 67108864);                    // 131072
    float* S1T  = (float*)(w + 67239936);                    // 131072
    float* W2T  = (float*)(w + 67371008);                    // 32768
    float* S2T  = (float*)(w + 67403776);                    // 32768
    float* hnm  = (float*)(w + 67436544);                    // 4096

    hipLaunchKernelGGL(fft_prep_kernel, dim3(1902), dim3(1024), 0, stream,
                       x, hb, hnm, W0, A0, Wb0, Sb0, W1, A1, W2, A2, W1T, S1T, W2T, S2T);
    hipLaunchKernelGGL(gemm0_kernel, dim3(8, 4, 16), dim3(256), 0, stream, hb, Wb0, Sb0, Py, Pp);
    hipLaunchKernelGGL(combine0_kernel, dim3(1024), dim3(256), 0, stream, Py, Pp, hnm, b0, eta0, g0, be0, h1, c1);
    hipLaunchKernelGGL(tail_kernel, dim3(256), dim3(256), 0, stream, h1, c1, W1T, S1T, b1, eta1, g1, be1,
                       W2T, S2T, b2, eta2, g2, be2, hw, hbod, out);
}

// Round 8
// 266.048 us; speedup vs baseline: 1.1049x; 1.1049x over previous
//
#include <hip/hip_runtime.h>
#include <hip/hip_bf16.h>
#include <math.h>

typedef short bf16x8 __attribute__((ext_vector_type(8)));
typedef float f32x4 __attribute__((ext_vector_type(4)));

static __device__ __forceinline__ unsigned short f2bf(float f) {
    unsigned int u = __float_as_uint(f);
    unsigned int r = (u + 0x7fffu + ((u >> 16) & 1u)) >> 16;
    return (unsigned short)r;
}

// elementwise square of a bf16x8 fragment (bf16 -> f32 -> square -> bf16 rne)
static __device__ __forceinline__ bf16x8 sq_bf16x8(bf16x8 a) {
    bf16x8 r;
    #pragma unroll
    for (int i = 0; i < 8; ++i) {
        unsigned int u = ((unsigned int)(unsigned short)a[i]) << 16;
        float f = __uint_as_float(u);
        f *= f;
        r[i] = (short)f2bf(f);
    }
    return r;
}

static __device__ __forceinline__ float gelu_f(float x) {
    return 0.5f * x * (1.f + erff(x * 0.70710678118654752f));
}

// async global->LDS, 16B per lane; LDS dest is wave-uniform base + lane*16
static __device__ __forceinline__ void gload_lds16(const void* g, void* l) {
    __builtin_amdgcn_global_load_lds(
        (const __attribute__((address_space(1))) unsigned int*)g,
        (__attribute__((address_space(3))) unsigned int*)l, 16, 0, 0);
}

// LDS index skew for FFT buffers
static __device__ __forceinline__ int ldsmap(int i) { return i + (i >> 6); }

static __device__ __forceinline__ int rev4(int k) {
    int d0 = k % 10; k /= 10;
    int d1 = k % 10; k /= 10;
    int d2 = k % 10; int d3 = k / 10;
    return d0 * 1000 + d1 * 100 + d2 * 10 + d3;
}

// forward 5-point DFT (W5 = e^{-2pi i/5}), Winograd-style
static __device__ __forceinline__ void dft5(
    float a0r, float a0i, float a1r, float a1i, float a2r, float a2i,
    float a3r, float a3i, float a4r, float a4i,
    float* Xr, float* Xi)
{
    const float c1 = 0.30901699437494742f, c2 = -0.80901699437494745f;
    const float s1 = 0.95105651629515357f, s2 = 0.58778525229247312f;
    float t1r = a1r + a4r, t1i = a1i + a4i;
    float d1r = a1r - a4r, d1i = a1i - a4i;
    float t2r = a2r + a3r, t2i = a2i + a3i;
    float d2r = a2r - a3r, d2i = a2i - a3i;
    Xr[0] = a0r + t1r + t2r; Xi[0] = a0i + t1i + t2i;
    float m1r = a0r + c1 * t1r + c2 * t2r, m1i = a0i + c1 * t1i + c2 * t2i;
    float m2r = a0r + c2 * t1r + c1 * t2r, m2i = a0i + c2 * t1i + c1 * t2i;
    float n1r = s1 * d1r + s2 * d2r, n1i = s1 * d1i + s2 * d2i;
    float n2r = s2 * d1r - s1 * d2r, n2i = s2 * d1i - s1 * d2i;
    Xr[1] = m1r + n1i; Xi[1] = m1i - n1r;
    Xr[4] = m1r - n1i; Xi[4] = m1i + n1r;
    Xr[2] = m2r + n2i; Xi[2] = m2i - n2r;
    Xr[3] = m2r - n2i; Xi[3] = m2i + n2r;
}

// One radix-10 DIF stage, specialized per stage index:
// S=0: g=0, j=w, fused mean-subtract. S=3: g=w, j=0, twiddles == 1 (skipped).
template<int S>
static __device__ __forceinline__ void radix10_stage(
    float* __restrict__ reb, float* __restrict__ imb, int tid, float mean)
{
    constexpr int L  = (S == 0) ? 1000 : (S == 1) ? 100 : (S == 2) ? 10 : 1;
    constexpr int SC = (S == 0) ? 1 : (S == 1) ? 10 : (S == 2) ? 100 : 1000;
    constexpr bool TW = (S != 3);

    const float WR[5] = {1.f, 0.80901699437494745f, 0.30901699437494742f,
                         -0.30901699437494742f, -0.80901699437494745f};
    const float WI[5] = {0.f, -0.58778525229247312f, -0.95105651629515357f,
                         -0.95105651629515357f, -0.58778525229247312f};

    for (int w = tid; w < 1000; w += 512) {
        int g, j;
        if (S == 0)      { g = 0; j = w; }
        else if (S == 3) { g = w; j = 0; }
        else             { g = w / L; j = w - g * L; }
        const int base = g * (10 * L) + j;

        float ar[10], ai[10];
        #pragma unroll
        for (int u = 0; u < 10; ++u) {
            int idx = ldsmap(base + u * L);
            ar[u] = reb[idx];
            ai[u] = imb[idx];
        }
        if (S == 0) {
            #pragma unroll
            for (int u = 0; u < 10; ++u) { ar[u] -= mean; ai[u] -= mean; }
        }

        float Er[5], Ei[5], Or[5], Oi[5];
        dft5(ar[0], ai[0], ar[2], ai[2], ar[4], ai[4], ar[6], ai[6], ar[8], ai[8], Er, Ei);
        dft5(ar[1], ai[1], ar[3], ai[3], ar[5], ai[5], ar[7], ai[7], ar[9], ai[9], Or, Oi);
        #pragma unroll
        for (int k = 1; k < 5; ++k) {
            float tr = Or[k] * WR[k] - Oi[k] * WI[k];
            Oi[k] = Or[k] * WI[k] + Oi[k] * WR[k];
            Or[k] = tr;
        }

        if (TW) {
            const float ang = (float)(j * SC) * -6.28318530717958648e-4f;
            float w1c, w1s;
            __sincosf(ang, &w1s, &w1c);
            float twr[10], twi[10];
            twr[0] = 1.f; twi[0] = 0.f;
            #pragma unroll
            for (int t = 1; t < 10; ++t) {
                twr[t] = twr[t - 1] * w1c - twi[t - 1] * w1s;
                twi[t] = twr[t - 1] * w1s + twi[t - 1] * w1c;
            }
            #pragma unroll
            for (int k = 0; k < 5; ++k) {
                float xr0 = Er[k] + Or[k], xi0 = Ei[k] + Oi[k];
                float xr1 = Er[k] - Or[k], xi1 = Ei[k] - Oi[k];
                int i0 = ldsmap(base + k * L);
                int i1 = ldsmap(base + (k + 5) * L);
                if (k == 0) {
                    reb[i0] = xr0;
                    imb[i0] = xi0;
                } else {
                    reb[i0] = xr0 * twr[k] - xi0 * twi[k];
                    imb[i0] = xr0 * twi[k] + xi0 * twr[k];
                }
                reb[i1] = xr1 * twr[k + 5] - xi1 * twi[k + 5];
                imb[i1] = xr1 * twi[k + 5] + xi1 * twr[k + 5];
            }
        } else {
            #pragma unroll
            for (int k = 0; k < 5; ++k) {
                int i0 = ldsmap(base + k * L);
                int i1 = ldsmap(base + (k + 5) * L);
                reb[i0] = Er[k] + Or[k]; imb[i0] = Ei[k] + Oi[k];
                reb[i1] = Er[k] - Or[k]; imb[i1] = Ei[k] - Oi[k];
            }
        }
    }
}

// ---------------------------------------------------------------------------
// Fused FFT + prep (R6 structure: 512 thr, 1 row/block, 2 blocks/CU).
// Blocks [0,1024): FFT rows -> h bf16 (padded) + hnorm. [1024,3804): prep.
// ---------------------------------------------------------------------------
__global__ __launch_bounds__(512, 4)
void fft_prep_kernel(const float* __restrict__ x,
                     unsigned short* __restrict__ hb,
                     float* __restrict__ hnorm,
                     const float* __restrict__ W0, const float* __restrict__ A0,
                     unsigned short* __restrict__ Wb, unsigned short* __restrict__ Sb,
                     const float* __restrict__ W1, const float* __restrict__ A1,
                     const float* __restrict__ W2, const float* __restrict__ A2,
                     float* __restrict__ W1T, float* __restrict__ S1T,
                     float* __restrict__ W2T, float* __restrict__ S2T)
{
    if (blockIdx.x >= 1024) {
        // ---- prep path ----
        int idx = (blockIdx.x - 1024) * 512 + threadIdx.x;
        if (idx < 1280128) {
            const bool isW = idx < 640064;
            const int f4 = isW ? idx : idx - 640064;
            const float* src = isW ? W0 : A0;
            unsigned short* dst = isW ? Wb : Sb;
            float4 v = ((const float4*)src)[f4];
            float e[4] = {v.x, v.y, v.z, v.w};
            int flat = f4 * 4;
            int row = flat / 10001;
            int col = flat - row * 10001;
            #pragma unroll
            for (int i = 0; i < 4; ++i) {
                if (col == 10001) { row++; col = 0; }
                float val = isW ? e[i] : 1.f / (1.f + expf(-e[i]));
                dst[(size_t)row * 10240 + col] = f2bf(val);
                col++;
            }
        } else if (idx < 1341312) {
            int i = idx - 1280128;              // 256*239 pads
            int row = i / 239;
            int col = 10001 + (i - row * 239);
            Wb[(size_t)row * 10240 + col] = 0;
            Sb[(size_t)row * 10240 + col] = 0;
        } else if (idx < 1423232) {
            int o = idx - 1341312;              // 0..81919
            if (o < 32768) {
                int d = o >> 7, h = o & 127;
                W1T[o] = W1[h * 256 + d];
            } else if (o < 65536) {
                int p = o - 32768;
                int d = p >> 7, h = p & 127;
                S1T[p] = 1.f / (1.f + expf(-A1[h * 256 + d]));
            } else if (o < 73728) {
                int p = o - 65536;
                int d = p >> 6, h = p & 63;
                W2T[p] = W2[h * 128 + d];
            } else {
                int p = o - 73728;
                int d = p >> 6, h = p & 63;
                S2T[p] = 1.f / (1.f + expf(-A2[h * 128 + d]));
            }
        }
        return;
    }

    // ---- FFT path ----
    __shared__ float reb[10156];
    __shared__ float imb[10156];
    __shared__ float redbuf[8];

    const int b = blockIdx.x;
    const int tid = threadIdx.x;
    const int lane = tid & 63;
    const int wv = tid >> 6;
    const float* xr = x + (size_t)b * 20000;

    // vectorized load + pack + row-sum (5000 float4s)
    float sum = 0.f;
    for (int i4 = tid; i4 < 5000; i4 += 512) {
        float4 v = ((const float4*)xr)[i4];
        sum += v.x + v.y + v.z + v.w;
        int n = i4 * 2;
        reb[ldsmap(n)]     = v.x; imb[ldsmap(n)]     = v.y;
        reb[ldsmap(n + 1)] = v.z; imb[ldsmap(n + 1)] = v.w;
    }
    #pragma unroll
    for (int o = 32; o; o >>= 1) sum += __shfl_xor(sum, o);
    __syncthreads();                 // pack complete + redbuf guard
    if (lane == 0) redbuf[wv] = sum;
    __syncthreads();
    float tot = 0.f;
    #pragma unroll
    for (int i = 0; i < 8; ++i) tot += redbuf[i];
    const float mean = tot * (1.f / 20000.f);

    radix10_stage<0>(reb, imb, tid, mean);
    __syncthreads();
    radix10_stage<1>(reb, imb, tid, 0.f);
    __syncthreads();
    radix10_stage<2>(reb, imb, tid, 0.f);
    __syncthreads();
    radix10_stage<3>(reb, imb, tid, 0.f);
    __syncthreads();

    // real-FFT untangle + log(1+|X|)
    float sumsq = 0.f;
    unsigned short* hrow = hb + (size_t)b * 10240;
    #pragma unroll
    for (int i = 0; i < 20; ++i) {
        int k = tid + i * 512;
        float hval = 0.f;
        if (k <= 10000) {
            int k1 = (k == 10000) ? 0 : k;
            int k2 = (k1 == 0) ? 0 : 10000 - k1;
            int i1 = ldsmap(rev4(k1));
            int i2 = ldsmap(rev4(k2));
            float zr = reb[i1], zi = imb[i1];
            float wr = reb[i2], wi = imb[i2];
            float er = 0.5f * (zr + wr);
            float ei = 0.5f * (zi - wi);
            float odr = 0.5f * (zi + wi);
            float odi = -0.5f * (zr - wr);
            float ct, st;
            __sincosf((float)k * -3.14159265358979324e-4f, &st, &ct);
            float xre = er + ct * odr - st * odi;
            float xim = ei + ct * odi + st * odr;
            hval = __logf(1.f + sqrtf(xre * xre + xim * xim));
        }
        hrow[k] = f2bf(hval);
        sumsq += hval * hval;
    }
    #pragma unroll
    for (int o = 32; o; o >>= 1) sumsq += __shfl_xor(sumsq, o);
    __syncthreads();
    if (lane == 0) redbuf[wv] = sumsq;
    __syncthreads();
    if (tid == 0) {
        float tsq = 0.f;
        #pragma unroll
        for (int i = 0; i < 8; ++i) tsq += redbuf[i];
        hnorm[b] = 1.f / (sqrtf(tsq) + 1e-8f);
    }
}

// ---------------------------------------------------------------------------
// Layer-0 dual GEMM: Y = h*W0^T, P = (h^2)*S0^T (1/||h|| applied downstream).
// BM=128 BN=64 BK=64, split-K=16. grid (8,4,16) x 256. LDS 32 KB.
// ---------------------------------------------------------------------------
__global__ __launch_bounds__(256, 2)
void gemm0_kernel(const unsigned short* __restrict__ hb,
                  const unsigned short* __restrict__ Wb, const unsigned short* __restrict__ Sb,
                  float* __restrict__ Py, float* __restrict__ Pp)
{
    __shared__ unsigned short Ah[128 * 64];
    __shared__ unsigned short Bw[64 * 64];
    __shared__ unsigned short Bs[64 * 64];

    const int t = threadIdx.x;
    const int b0 = blockIdx.x * 128;
    const int n0 = blockIdx.y * 64;
    const int z = blockIdx.z;
    const int lane = t & 63;
    const int wv = t >> 6;
    const int ml = lane & 15;
    const int q4 = lane >> 4;
    const int s0 = q4 ^ (ml & 7);

    const int sub = lane >> 3;
    const int sl = lane & 7;
    const int gsw = sl ^ sub;

    f32x4 accY[2][4], accP[2][4];
    #pragma unroll
    for (int mt = 0; mt < 2; ++mt)
        #pragma unroll
        for (int nt = 0; nt < 4; ++nt) {
            accY[mt][nt] = (f32x4){0.f, 0.f, 0.f, 0.f};
            accP[mt][nt] = (f32x4){0.f, 0.f, 0.f, 0.f};
        }

    const int kbase = z * 640;

    for (int step = 0; step < 10; ++step) {
        const int k0 = kbase + step * 64;
        __syncthreads();
        #pragma unroll
        for (int j = 0; j < 4; ++j) {
            const int c = wv * 4 + j;
            const size_t go = (size_t)(b0 + c * 8 + sub) * 10240 + k0 + gsw * 8;
            gload_lds16(&hb[go], &Ah[c * 512]);
        }
        #pragma unroll
        for (int j = 0; j < 2; ++j) {
            const int c = wv * 2 + j;
            const size_t go = (size_t)(n0 + c * 8 + sub) * 10240 + k0 + gsw * 8;
            gload_lds16(&Wb[go], &Bw[c * 512]);
            gload_lds16(&Sb[go], &Bs[c * 512]);
        }
        __syncthreads();

        #pragma unroll
        for (int kk = 0; kk < 2; ++kk) {
            const int slot = (s0 ^ (kk << 2)) << 3;
            bf16x8 ah[2], ac[2], bw[4], bs[4];
            #pragma unroll
            for (int mt = 0; mt < 2; ++mt) {
                int mrow = wv * 32 + mt * 16 + ml;
                ah[mt] = *(const bf16x8*)&Ah[mrow * 64 + slot];
                ac[mt] = sq_bf16x8(ah[mt]);
            }
            #pragma unroll
            for (int nt = 0; nt < 4; ++nt) {
                int nrow = nt * 16 + ml;
                bw[nt] = *(const bf16x8*)&Bw[nrow * 64 + slot];
                bs[nt] = *(const bf16x8*)&Bs[nrow * 64 + slot];
            }
            #pragma unroll
            for (int mt = 0; mt < 2; ++mt)
                #pragma unroll
                for (int nt = 0; nt < 4; ++nt) {
                    accY[mt][nt] = __builtin_amdgcn_mfma_f32_16x16x32_bf16(ah[mt], bw[nt], accY[mt][nt], 0, 0, 0);
                    accP[mt][nt] = __builtin_amdgcn_mfma_f32_16x16x32_bf16(ac[mt], bs[nt], accP[mt][nt], 0, 0, 0);
                }
        }
    }

    const int rq = q4 * 4;
    #pragma unroll
    for (int mt = 0; mt < 2; ++mt)
        #pragma unroll
        for (int nt = 0; nt < 4; ++nt)
            #pragma unroll
            for (int r = 0; r < 4; ++r) {
                int m = b0 + wv * 32 + mt * 16 + rq + r;
                int n = n0 + nt * 16 + ml;
                size_t o = ((size_t)z * 1024 + m) * 256 + n;
                Py[o] = accY[mt][nt][r];
                Pp[o] = accP[mt][nt][r];
            }
}

// ---------------------------------------------------------------------------
// Fused combine + tail: split-K reduce + layer-0 plastic/LN/GELU (in LDS),
// then layers 1,2 + head. 4 rows per block, grid 256 x 256 thr.
// ---------------------------------------------------------------------------
__global__ __launch_bounds__(256)
void combine_tail_kernel(const float* __restrict__ Py, const float* __restrict__ Pp,
                 const float* __restrict__ hnorm,
                 const float* __restrict__ b0v, const float* __restrict__ eta0p,
                 const float* __restrict__ g0, const float* __restrict__ be0,
                 const float* __restrict__ W1T, const float* __restrict__ S1T,
                 const float* __restrict__ b1, const float* __restrict__ eta1p,
                 const float* __restrict__ g1, const float* __restrict__ be1,
                 const float* __restrict__ W2T, const float* __restrict__ S2T,
                 const float* __restrict__ b2, const float* __restrict__ eta2p,
                 const float* __restrict__ g2, const float* __restrict__ be2,
                 const float* __restrict__ hw, const float* __restrict__ hbod,
                 float* __restrict__ out)
{
    __shared__ float sh[4][256];
    __shared__ float sc[4][256];
    __shared__ float sv[4][128];
    __shared__ float sh2[4][128];
    __shared__ float sc2[4][128];
    __shared__ float sv2[4][64];
    __shared__ float redA[4][4];     // [wave][row]
    __shared__ float redB[4][4];

    const int t = threadIdx.x;       // column 0..255
    const int b0 = blockIdx.x * 4;
    const int lane = t & 63;
    const int wv = t >> 6;

    // ---- combine phase: split-K reduce + plastic for 4 rows ----
    const float e0 = eta0p[0];
    const float bias0 = b0v[t];
    float v[4];
    #pragma unroll
    for (int r = 0; r < 4; ++r) {
        float ys = 0.f, ps = 0.f;
        #pragma unroll 4
        for (int s = 0; s < 16; ++s) {
            size_t o = ((size_t)s * 1024 + b0 + r) * 256 + t;
            ys += Py[o];
            ps += Pp[o];
        }
        ps *= hnorm[b0 + r];
        float y = ys + bias0;
        v[r] = y + e0 * tanhf(y) * ps;
    }

    // LN(256) over columns, all 4 rows in one barrier round
    float s1[4], s2[4];
    #pragma unroll
    for (int r = 0; r < 4; ++r) { s1[r] = v[r]; s2[r] = v[r] * v[r]; }
    #pragma unroll
    for (int o = 32; o; o >>= 1)
        #pragma unroll
        for (int r = 0; r < 4; ++r) { s1[r] += __shfl_xor(s1[r], o); s2[r] += __shfl_xor(s2[r], o); }
    if (lane == 0)
        #pragma unroll
        for (int r = 0; r < 4; ++r) { redA[wv][r] = s1[r]; redB[wv][r] = s2[r]; }
    __syncthreads();

    const float gg = g0[t], bb = be0[t];
    float gl[4], s3[4];
    #pragma unroll
    for (int r = 0; r < 4; ++r) {
        float sum = redA[0][r] + redA[1][r] + redA[2][r] + redA[3][r];
        float sumsq = redB[0][r] + redB[1][r] + redB[2][r] + redB[3][r];
        float mu = sum * (1.f / 256.f);
        float var = sumsq * (1.f / 256.f) - mu * mu;
        float u = (v[r] - mu) * rsqrtf(var + 1e-5f) * gg + bb;
        gl[r] = gelu_f(u);
        s3[r] = gl[r] * gl[r];
    }
    #pragma unroll
    for (int o = 32; o; o >>= 1)
        #pragma unroll
        for (int r = 0; r < 4; ++r) s3[r] += __shfl_xor(s3[r], o);
    __syncthreads();                 // redA reuse guard
    if (lane == 0)
        #pragma unroll
        for (int r = 0; r < 4; ++r) redA[wv][r] = s3[r];
    __syncthreads();
    #pragma unroll
    for (int r = 0; r < 4; ++r) {
        float gsq = redA[0][r] + redA[1][r] + redA[2][r] + redA[3][r];
        float inv = 1.f / (sqrtf(gsq) + 1e-8f);
        sh[r][t] = gl[r];
        sc[r][t] = gl[r] * gl[r] * inv;
    }
    __syncthreads();

    // ---- layer 1: 128 outputs x 4 rows; each thread 2 rows ----
    const int hcol = t & 127;
    const int r2 = t >> 7;           // 0..1
    float ya[2] = {0.f, 0.f};
    float pa[2] = {0.f, 0.f};
    for (int d = 0; d < 256; ++d) {
        float w = W1T[d * 128 + hcol];
        float s = S1T[d * 128 + hcol];
        #pragma unroll
        for (int i = 0; i < 2; ++i) {
            int r = r2 * 2 + i;
            ya[i] += sh[r][d] * w;
            pa[i] += sc[r][d] * s;
        }
    }
    const float e1 = eta1p[0];
    #pragma unroll
    for (int i = 0; i < 2; ++i) {
        int r = r2 * 2 + i;
        float y = ya[i] + b1[hcol];
        sv[r][hcol] = y + e1 * tanhf(y) * pa[i];
    }
    __syncthreads();

    // LN(128) + gelu + c2: wave per row
    {
        int r = wv;
        float v0 = sv[r][lane];
        float v1 = sv[r][lane + 64];
        float s = v0 + v1, sq = v0 * v0 + v1 * v1;
        #pragma unroll
        for (int o = 32; o; o >>= 1) { s += __shfl_xor(s, o); sq += __shfl_xor(sq, o); }
        float mu = s * (1.f / 128.f);
        float var = sq * (1.f / 128.f) - mu * mu;
        float rs = rsqrtf(var + 1e-5f);
        float u0 = (v0 - mu) * rs * g1[lane] + be1[lane];
        float u1 = (v1 - mu) * rs * g1[lane + 64] + be1[lane + 64];
        float ge0 = gelu_f(u0);
        float ge1 = gelu_f(u1);
        float gsq = ge0 * ge0 + ge1 * ge1;
        #pragma unroll
        for (int o = 32; o; o >>= 1) gsq += __shfl_xor(gsq, o);
        float inv = 1.f / (sqrtf(gsq) + 1e-8f);
        sh2[r][lane] = ge0; sh2[r][lane + 64] = ge1;
        sc2[r][lane] = ge0 * ge0 * inv; sc2[r][lane + 64] = ge1 * ge1 * inv;
    }
    __syncthreads();

    // ---- layer 2: 64 outputs x 4 rows; one item per thread ----
    const int h2c = t & 63;
    const int r4 = t >> 6;           // 0..3
    float yb = 0.f, pb = 0.f;
    for (int d = 0; d < 128; ++d) {
        yb += sh2[r4][d] * W2T[d * 64 + h2c];
        pb += sc2[r4][d] * S2T[d * 64 + h2c];
    }
    {
        const float e2 = eta2p[0];
        float y = yb + b2[h2c];
        sv2[r4][h2c] = y + e2 * tanhf(y) * pb;
    }
    __syncthreads();

    // LN(64) + gelu + head: wave per row
    {
        int r = wv;
        float v0 = sv2[r][lane];
        float s = v0, sq = v0 * v0;
        #pragma unroll
        for (int o = 32; o; o >>= 1) { s += __shfl_xor(s, o); sq += __shfl_xor(sq, o); }
        float mu = s * (1.f / 64.f);
        float var = sq * (1.f / 64.f) - mu * mu;
        float rs = rsqrtf(var + 1e-5f);
        float u = (v0 - mu) * rs * g2[lane] + be2[lane];
        float g = gelu_f(u);
        float hc = g * hw[lane];
        #pragma unroll
        for (int o = 32; o; o >>= 1) hc += __shfl_xor(hc, o);
        if (lane == 0) out[b0 + r] = hc + hbod[0];
    }
}

// ---------------------------------------------------------------------------
extern "C" void kernel_launch(void* const* d_in, const int* in_sizes, int n_in,
                              void* d_out, int out_size, void* d_ws, size_t ws_size,
                              hipStream_t stream)
{
    const float* x    = (const float*)d_in[0];
    const float* W0   = (const float*)d_in[1];
    const float* A0   = (const float*)d_in[2];
    const float* b0   = (const float*)d_in[3];
    const float* eta0 = (const float*)d_in[4];
    const float* g0   = (const float*)d_in[5];
    const float* be0  = (const float*)d_in[6];
    const float* W1   = (const float*)d_in[7];
    const float* A1   = (const float*)d_in[8];
    const float* b1   = (const float*)d_in[9];
    const float* eta1 = (const float*)d_in[10];
    const float* g1   = (const float*)d_in[11];
    const float* be1  = (const float*)d_in[12];
    const float* W2   = (const float*)d_in[13];
    const float* A2   = (const float*)d_in[14];
    const float* b2   = (const float*)d_in[15];
    const float* eta2 = (const float*)d_in[16];
    const float* g2   = (const float*)d_in[17];
    const float* be2  = (const float*)d_in[18];
    const float* hw   = (const float*)d_in[19];
    const float* hbod = (const float*)d_in[20];
    float* out = (float*)d_out;

    char* w = (char*)d_ws;
    unsigned short* hb  = (unsigned short*)(w + 0);          // 20971520
    unsigned short* Wb0 = (unsigned short*)(w + 20971520);   // 5242880
    unsigned short* Sb0 = (unsigned short*)(w + 26214400);   // 5242880
    float* Py   = (float*)(w + 31457280);                    // 16777216
    float* Pp   = (float*)(w + 48234496);                    // 16777216
    float* W1T  = (float*)(w + 65011712);                    // 131072
    float* S1T  = (float*)(w + 65142784);                    // 131072
    float* W2T  = (float*)(w + 65273856);                    // 32768
    float* S2T  = (float*)(w + 65306624);                    // 32768
    float* hnm  = (float*)(w + 65339392);                    // 4096
    // total = 65343488 bytes

    hipLaunchKernelGGL(fft_prep_kernel, dim3(3804), dim3(512), 0, stream,
                       x, hb, hnm, W0, A0, Wb0, Sb0, W1, A1, W2, A2, W1T, S1T, W2T, S2T);
    hipLaunchKernelGGL(gemm0_kernel, dim3(8, 4, 16), dim3(256), 0, stream, hb, Wb0, Sb0, Py, Pp);
    hipLaunchKernelGGL(combine_tail_kernel, dim3(256), dim3(256), 0, stream, Py, Pp, hnm,
                       b0, eta0, g0, be0, W1T, S1T, b1, eta1, g1, be1,
                       W2T, S2T, b2, eta2, g2, be2, hw, hbod, out);
}

// Round 9
// 252.801 us; speedup vs baseline: 1.1628x; 1.0524x over previous
//
#include <hip/hip_runtime.h>
#include <hip/hip_bf16.h>
#include <math.h>

typedef short bf16x8 __attribute__((ext_vector_type(8)));
typedef float f32x4 __attribute__((ext_vector_type(4)));

static __device__ __forceinline__ unsigned short f2bf(float f) {
    unsigned int u = __float_as_uint(f);
    unsigned int r = (u + 0x7fffu + ((u >> 16) & 1u)) >> 16;
    return (unsigned short)r;
}

// elementwise square of a bf16x8 fragment (bf16 -> f32 -> square -> bf16 rne)
static __device__ __forceinline__ bf16x8 sq_bf16x8(bf16x8 a) {
    bf16x8 r;
    #pragma unroll
    for (int i = 0; i < 8; ++i) {
        unsigned int u = ((unsigned int)(unsigned short)a[i]) << 16;
        float f = __uint_as_float(u);
        f *= f;
        r[i] = (short)f2bf(f);
    }
    return r;
}

static __device__ __forceinline__ float gelu_f(float x) {
    return 0.5f * x * (1.f + erff(x * 0.70710678118654752f));
}

// async global->LDS, 16B per lane; LDS dest is wave-uniform base + lane*16
static __device__ __forceinline__ void gload_lds16(const void* g, void* l) {
    __builtin_amdgcn_global_load_lds(
        (const __attribute__((address_space(1))) unsigned int*)g,
        (__attribute__((address_space(3))) unsigned int*)l, 16, 0, 0);
}

// LDS index skew for FFT buffers
static __device__ __forceinline__ int ldsmap(int i) { return i + (i >> 6); }

static __device__ __forceinline__ int rev4(int k) {
    int d0 = k % 10; k /= 10;
    int d1 = k % 10; k /= 10;
    int d2 = k % 10; int d3 = k / 10;
    return d0 * 1000 + d1 * 100 + d2 * 10 + d3;
}

// forward 5-point DFT (W5 = e^{-2pi i/5}), Winograd-style
static __device__ __forceinline__ void dft5(
    float a0r, float a0i, float a1r, float a1i, float a2r, float a2i,
    float a3r, float a3i, float a4r, float a4i,
    float* Xr, float* Xi)
{
    const float c1 = 0.30901699437494742f, c2 = -0.80901699437494745f;
    const float s1 = 0.95105651629515357f, s2 = 0.58778525229247312f;
    float t1r = a1r + a4r, t1i = a1i + a4i;
    float d1r = a1r - a4r, d1i = a1i - a4i;
    float t2r = a2r + a3r, t2i = a2i + a3i;
    float d2r = a2r - a3r, d2i = a2i - a3i;
    Xr[0] = a0r + t1r + t2r; Xi[0] = a0i + t1i + t2i;
    float m1r = a0r + c1 * t1r + c2 * t2r, m1i = a0i + c1 * t1i + c2 * t2i;
    float m2r = a0r + c2 * t1r + c1 * t2r, m2i = a0i + c2 * t1i + c1 * t2i;
    float n1r = s1 * d1r + s2 * d2r, n1i = s1 * d1i + s2 * d2i;
    float n2r = s2 * d1r - s1 * d2r, n2i = s2 * d1i - s1 * d2i;
    Xr[1] = m1r + n1i; Xi[1] = m1i - n1r;
    Xr[4] = m1r - n1i; Xi[4] = m1i + n1r;
    Xr[2] = m2r + n2i; Xi[2] = m2i - n2r;
    Xr[3] = m2r - n2i; Xi[3] = m2i + n2r;
}

// core of a radix-10 DIF butterfly given 10 loaded taps; writes LDS (twiddled)
template<int S>
static __device__ __forceinline__ void radix10_core(
    float* __restrict__ reb, float* __restrict__ imb,
    const float* ar, const float* ai, int base, int j)
{
    constexpr int L  = (S == 0) ? 1000 : (S == 1) ? 100 : (S == 2) ? 10 : 1;
    constexpr int SC = (S == 0) ? 1 : (S == 1) ? 10 : (S == 2) ? 100 : 1000;
    constexpr bool TW = (S != 3);

    const float WR[5] = {1.f, 0.80901699437494745f, 0.30901699437494742f,
                         -0.30901699437494742f, -0.80901699437494745f};
    const float WI[5] = {0.f, -0.58778525229247312f, -0.95105651629515357f,
                         -0.95105651629515357f, -0.58778525229247312f};

    float Er[5], Ei[5], Or[5], Oi[5];
    dft5(ar[0], ai[0], ar[2], ai[2], ar[4], ai[4], ar[6], ai[6], ar[8], ai[8], Er, Ei);
    dft5(ar[1], ai[1], ar[3], ai[3], ar[5], ai[5], ar[7], ai[7], ar[9], ai[9], Or, Oi);
    #pragma unroll
    for (int k = 1; k < 5; ++k) {
        float tr = Or[k] * WR[k] - Oi[k] * WI[k];
        Oi[k] = Or[k] * WI[k] + Oi[k] * WR[k];
        Or[k] = tr;
    }

    if (TW) {
        const float ang = (float)(j * SC) * -6.28318530717958648e-4f;
        float w1c, w1s;
        __sincosf(ang, &w1s, &w1c);
        float twr[10], twi[10];
        twr[0] = 1.f; twi[0] = 0.f;
        #pragma unroll
        for (int t = 1; t < 10; ++t) {
            twr[t] = twr[t - 1] * w1c - twi[t - 1] * w1s;
            twi[t] = twr[t - 1] * w1s + twi[t - 1] * w1c;
        }
        #pragma unroll
        for (int k = 0; k < 5; ++k) {
            float xr0 = Er[k] + Or[k], xi0 = Ei[k] + Oi[k];
            float xr1 = Er[k] - Or[k], xi1 = Ei[k] - Oi[k];
            int i0 = ldsmap(base + k * L);
            int i1 = ldsmap(base + (k + 5) * L);
            if (k == 0) {
                reb[i0] = xr0;
                imb[i0] = xi0;
            } else {
                reb[i0] = xr0 * twr[k] - xi0 * twi[k];
                imb[i0] = xr0 * twi[k] + xi0 * twr[k];
            }
            reb[i1] = xr1 * twr[k + 5] - xi1 * twi[k + 5];
            imb[i1] = xr1 * twi[k + 5] + xi1 * twr[k + 5];
        }
    } else {
        #pragma unroll
        for (int k = 0; k < 5; ++k) {
            int i0 = ldsmap(base + k * L);
            int i1 = ldsmap(base + (k + 5) * L);
            reb[i0] = Er[k] + Or[k]; imb[i0] = Ei[k] + Oi[k];
            reb[i1] = Er[k] - Or[k]; imb[i1] = Ei[k] - Oi[k];
        }
    }
}

// radix-10 DIF stage for S>=1 (reads LDS)
template<int S>
static __device__ __forceinline__ void radix10_stage(
    float* __restrict__ reb, float* __restrict__ imb, int tid)
{
    constexpr int L = (S == 1) ? 100 : (S == 2) ? 10 : 1;
    for (int w = tid; w < 1000; w += 512) {
        int g, j;
        if (S == 3) { g = w; j = 0; }
        else        { g = w / L; j = w - g * L; }
        const int base = g * (10 * L) + j;
        float ar[10], ai[10];
        #pragma unroll
        for (int u = 0; u < 10; ++u) {
            int idx = ldsmap(base + u * L);
            ar[u] = reb[idx];
            ai[u] = imb[idx];
        }
        radix10_core<S>(reb, imb, ar, ai, base, j);
    }
}

// ---------------------------------------------------------------------------
// Fused FFT + prep. Blocks [0,1024): FFT rows (512 thr, 1 row/block, 81 KB
// LDS, 2 blocks/CU). Mean-subtraction eliminated algebraically (affects only
// bin 0, where centered X[0]=0 exactly -> h[0]=0 forced). Stage 0 fused with
// the global load: direct coalesced float2 taps -> butterfly -> LDS.
// Blocks [1024,3804): weight prep.
// ---------------------------------------------------------------------------
__global__ __launch_bounds__(512, 4)
void fft_prep_kernel(const float* __restrict__ x,
                     unsigned short* __restrict__ hb,
                     float* __restrict__ hnorm,
                     const float* __restrict__ W0, const float* __restrict__ A0,
                     unsigned short* __restrict__ Wb, unsigned short* __restrict__ Sb,
                     const float* __restrict__ W1, const float* __restrict__ A1,
                     const float* __restrict__ W2, const float* __restrict__ A2,
                     float* __restrict__ W1T, float* __restrict__ S1T,
                     float* __restrict__ W2T, float* __restrict__ S2T)
{
    if (blockIdx.x >= 1024) {
        // ---- prep path ----
        int idx = (blockIdx.x - 1024) * 512 + threadIdx.x;
        if (idx < 1280128) {
            const bool isW = idx < 640064;
            const int f4 = isW ? idx : idx - 640064;
            const float* src = isW ? W0 : A0;
            unsigned short* dst = isW ? Wb : Sb;
            float4 v = ((const float4*)src)[f4];
            float e[4] = {v.x, v.y, v.z, v.w};
            int flat = f4 * 4;
            int row = flat / 10001;
            int col = flat - row * 10001;
            #pragma unroll
            for (int i = 0; i < 4; ++i) {
                if (col == 10001) { row++; col = 0; }
                float val = isW ? e[i] : 1.f / (1.f + expf(-e[i]));
                dst[(size_t)row * 10240 + col] = f2bf(val);
                col++;
            }
        } else if (idx < 1341312) {
            int i = idx - 1280128;              // 256*239 pads
            int row = i / 239;
            int col = 10001 + (i - row * 239);
            Wb[(size_t)row * 10240 + col] = 0;
            Sb[(size_t)row * 10240 + col] = 0;
        } else if (idx < 1423232) {
            int o = idx - 1341312;              // 0..81919
            if (o < 32768) {
                int d = o >> 7, h = o & 127;
                W1T[o] = W1[h * 256 + d];
            } else if (o < 65536) {
                int p = o - 32768;
                int d = p >> 7, h = p & 127;
                S1T[p] = 1.f / (1.f + expf(-A1[h * 256 + d]));
            } else if (o < 73728) {
                int p = o - 65536;
                int d = p >> 6, h = p & 63;
                W2T[p] = W2[h * 128 + d];
            } else {
                int p = o - 73728;
                int d = p >> 6, h = p & 63;
                S2T[p] = 1.f / (1.f + expf(-A2[h * 128 + d]));
            }
        }
        return;
    }

    // ---- FFT path ----
    __shared__ float reb[10156];
    __shared__ float imb[10156];
    __shared__ float redbuf[8];

    const int b = blockIdx.x;
    const int tid = threadIdx.x;
    const int lane = tid & 63;
    const int wv = tid >> 6;

    // stage 0 fused with global load: z[n] = (x[2n], x[2n+1]) as float2
    const float2* z2 = (const float2*)(x + (size_t)b * 20000);
    for (int w = tid; w < 1000; w += 512) {
        float ar[10], ai[10];
        #pragma unroll
        for (int u = 0; u < 10; ++u) {
            float2 v = z2[w + u * 1000];
            ar[u] = v.x; ai[u] = v.y;
        }
        radix10_core<0>(reb, imb, ar, ai, w, w);
    }
    __syncthreads();
    radix10_stage<1>(reb, imb, tid);
    __syncthreads();
    radix10_stage<2>(reb, imb, tid);
    __syncthreads();
    radix10_stage<3>(reb, imb, tid);
    __syncthreads();

    // real-FFT untangle + log(1+|X|); h[0]=0 exactly (centered DC bin)
    float sumsq = 0.f;
    unsigned short* hrow = hb + (size_t)b * 10240;
    #pragma unroll
    for (int i = 0; i < 20; ++i) {
        int k = tid + i * 512;
        float hval = 0.f;
        if (k > 0 && k <= 10000) {
            int k1 = (k == 10000) ? 0 : k;
            int k2 = (k1 == 0) ? 0 : 10000 - k1;
            int i1 = ldsmap(rev4(k1));
            int i2 = ldsmap(rev4(k2));
            float zr = reb[i1], zi = imb[i1];
            float wr = reb[i2], wi = imb[i2];
            float er = 0.5f * (zr + wr);
            float ei = 0.5f * (zi - wi);
            float odr = 0.5f * (zi + wi);
            float odi = -0.5f * (zr - wr);
            float ct, st;
            __sincosf((float)k * -3.14159265358979324e-4f, &st, &ct);
            float xre = er + ct * odr - st * odi;
            float xim = ei + ct * odi + st * odr;
            hval = __logf(1.f + sqrtf(xre * xre + xim * xim));
        }
        hrow[k] = f2bf(hval);
        sumsq += hval * hval;
    }
    #pragma unroll
    for (int o = 32; o; o >>= 1) sumsq += __shfl_xor(sumsq, o);
    __syncthreads();
    if (lane == 0) redbuf[wv] = sumsq;
    __syncthreads();
    if (tid == 0) {
        float tsq = 0.f;
        #pragma unroll
        for (int i = 0; i < 8; ++i) tsq += redbuf[i];
        hnorm[b] = 1.f / (sqrtf(tsq) + 1e-8f);
    }
}

// ---------------------------------------------------------------------------
// Layer-0 dual GEMM: Y = h*W0^T, P = (h^2)*S0^T (1/||h|| applied downstream).
// BM=128 BN=64 BK=64, split-K=16. grid (8,4,16) x 256. LDS 32 KB.
// ---------------------------------------------------------------------------
__global__ __launch_bounds__(256, 2)
void gemm0_kernel(const unsigned short* __restrict__ hb,
                  const unsigned short* __restrict__ Wb, const unsigned short* __restrict__ Sb,
                  float* __restrict__ Py, float* __restrict__ Pp)
{
    __shared__ unsigned short Ah[128 * 64];
    __shared__ unsigned short Bw[64 * 64];
    __shared__ unsigned short Bs[64 * 64];

    const int t = threadIdx.x;
    const int b0 = blockIdx.x * 128;
    const int n0 = blockIdx.y * 64;
    const int z = blockIdx.z;
    const int lane = t & 63;
    const int wv = t >> 6;
    const int ml = lane & 15;
    const int q4 = lane >> 4;
    const int s0 = q4 ^ (ml & 7);

    const int sub = lane >> 3;
    const int sl = lane & 7;
    const int gsw = sl ^ sub;

    f32x4 accY[2][4], accP[2][4];
    #pragma unroll
    for (int mt = 0; mt < 2; ++mt)
        #pragma unroll
        for (int nt = 0; nt < 4; ++nt) {
            accY[mt][nt] = (f32x4){0.f, 0.f, 0.f, 0.f};
            accP[mt][nt] = (f32x4){0.f, 0.f, 0.f, 0.f};
        }

    const int kbase = z * 640;

    for (int step = 0; step < 10; ++step) {
        const int k0 = kbase + step * 64;
        __syncthreads();
        #pragma unroll
        for (int j = 0; j < 4; ++j) {
            const int c = wv * 4 + j;
            const size_t go = (size_t)(b0 + c * 8 + sub) * 10240 + k0 + gsw * 8;
            gload_lds16(&hb[go], &Ah[c * 512]);
        }
        #pragma unroll
        for (int j = 0; j < 2; ++j) {
            const int c = wv * 2 + j;
            const size_t go = (size_t)(n0 + c * 8 + sub) * 10240 + k0 + gsw * 8;
            gload_lds16(&Wb[go], &Bw[c * 512]);
            gload_lds16(&Sb[go], &Bs[c * 512]);
        }
        __syncthreads();

        #pragma unroll
        for (int kk = 0; kk < 2; ++kk) {
            const int slot = (s0 ^ (kk << 2)) << 3;
            bf16x8 ah[2], ac[2], bw[4], bs[4];
            #pragma unroll
            for (int mt = 0; mt < 2; ++mt) {
                int mrow = wv * 32 + mt * 16 + ml;
                ah[mt] = *(const bf16x8*)&Ah[mrow * 64 + slot];
                ac[mt] = sq_bf16x8(ah[mt]);
            }
            #pragma unroll
            for (int nt = 0; nt < 4; ++nt) {
                int nrow = nt * 16 + ml;
                bw[nt] = *(const bf16x8*)&Bw[nrow * 64 + slot];
                bs[nt] = *(const bf16x8*)&Bs[nrow * 64 + slot];
            }
            #pragma unroll
            for (int mt = 0; mt < 2; ++mt)
                #pragma unroll
                for (int nt = 0; nt < 4; ++nt) {
                    accY[mt][nt] = __builtin_amdgcn_mfma_f32_16x16x32_bf16(ah[mt], bw[nt], accY[mt][nt], 0, 0, 0);
                    accP[mt][nt] = __builtin_amdgcn_mfma_f32_16x16x32_bf16(ac[mt], bs[nt], accP[mt][nt], 0, 0, 0);
                }
        }
    }

    const int rq = q4 * 4;
    #pragma unroll
    for (int mt = 0; mt < 2; ++mt)
        #pragma unroll
        for (int nt = 0; nt < 4; ++nt)
            #pragma unroll
            for (int r = 0; r < 4; ++r) {
                int m = b0 + wv * 32 + mt * 16 + rq + r;
                int n = n0 + nt * 16 + ml;
                size_t o = ((size_t)z * 1024 + m) * 256 + n;
                Py[o] = accY[mt][nt][r];
                Pp[o] = accP[mt][nt][r];
            }
}

// ---------------------------------------------------------------------------
// Fused combine + tail: split-K reduce + layer-0 plastic/LN/GELU (in LDS),
// then layers 1,2 + head. 4 rows per block, grid 256 x 256 thr.
// ---------------------------------------------------------------------------
__global__ __launch_bounds__(256)
void combine_tail_kernel(const float* __restrict__ Py, const float* __restrict__ Pp,
                 const float* __restrict__ hnorm,
                 const float* __restrict__ b0v, const float* __restrict__ eta0p,
                 const float* __restrict__ g0, const float* __restrict__ be0,
                 const float* __restrict__ W1T, const float* __restrict__ S1T,
                 const float* __restrict__ b1, const float* __restrict__ eta1p,
                 const float* __restrict__ g1, const float* __restrict__ be1,
                 const float* __restrict__ W2T, const float* __restrict__ S2T,
                 const float* __restrict__ b2, const float* __restrict__ eta2p,
                 const float* __restrict__ g2, const float* __restrict__ be2,
                 const float* __restrict__ hw, const float* __restrict__ hbod,
                 float* __restrict__ out)
{
    __shared__ float sh[4][256];
    __shared__ float sc[4][256];
    __shared__ float sv[4][128];
    __shared__ float sh2[4][128];
    __shared__ float sc2[4][128];
    __shared__ float sv2[4][64];
    __shared__ float redA[4][4];     // [wave][row]
    __shared__ float redB[4][4];

    const int t = threadIdx.x;       // column 0..255
    const int b0 = blockIdx.x * 4;
    const int lane = t & 63;
    const int wv = t >> 6;

    // ---- combine phase: split-K reduce + plastic for 4 rows ----
    const float e0 = eta0p[0];
    const float bias0 = b0v[t];
    float v[4];
    #pragma unroll
    for (int r = 0; r < 4; ++r) {
        float ys = 0.f, ps = 0.f;
        #pragma unroll 4
        for (int s = 0; s < 16; ++s) {
            size_t o = ((size_t)s * 1024 + b0 + r) * 256 + t;
            ys += Py[o];
            ps += Pp[o];
        }
        ps *= hnorm[b0 + r];
        float y = ys + bias0;
        v[r] = y + e0 * tanhf(y) * ps;
    }

    // LN(256) over columns, all 4 rows in one barrier round
    float s1[4], s2[4];
    #pragma unroll
    for (int r = 0; r < 4; ++r) { s1[r] = v[r]; s2[r] = v[r] * v[r]; }
    #pragma unroll
    for (int o = 32; o; o >>= 1)
        #pragma unroll
        for (int r = 0; r < 4; ++r) { s1[r] += __shfl_xor(s1[r], o); s2[r] += __shfl_xor(s2[r], o); }
    if (lane == 0)
        #pragma unroll
        for (int r = 0; r < 4; ++r) { redA[wv][r] = s1[r]; redB[wv][r] = s2[r]; }
    __syncthreads();

    const float gg = g0[t], bb = be0[t];
    float gl[4], s3[4];
    #pragma unroll
    for (int r = 0; r < 4; ++r) {
        float sum = redA[0][r] + redA[1][r] + redA[2][r] + redA[3][r];
        float sumsq = redB[0][r] + redB[1][r] + redB[2][r] + redB[3][r];
        float mu = sum * (1.f / 256.f);
        float var = sumsq * (1.f / 256.f) - mu * mu;
        float u = (v[r] - mu) * rsqrtf(var + 1e-5f) * gg + bb;
        gl[r] = gelu_f(u);
        s3[r] = gl[r] * gl[r];
    }
    #pragma unroll
    for (int o = 32; o; o >>= 1)
        #pragma unroll
        for (int r = 0; r < 4; ++r) s3[r] += __shfl_xor(s3[r], o);
    __syncthreads();                 // redA reuse guard
    if (lane == 0)
        #pragma unroll
        for (int r = 0; r < 4; ++r) redA[wv][r] = s3[r];
    __syncthreads();
    #pragma unroll
    for (int r = 0; r < 4; ++r) {
        float gsq = redA[0][r] + redA[1][r] + redA[2][r] + redA[3][r];
        float inv = 1.f / (sqrtf(gsq) + 1e-8f);
        sh[r][t] = gl[r];
        sc[r][t] = gl[r] * gl[r] * inv;
    }
    __syncthreads();

    // ---- layer 1: 128 outputs x 4 rows; each thread 2 rows ----
    const int hcol = t & 127;
    const int r2 = t >> 7;           // 0..1
    float ya[2] = {0.f, 0.f};
    float pa[2] = {0.f, 0.f};
    for (int d = 0; d < 256; ++d) {
        float w = W1T[d * 128 + hcol];
        float s = S1T[d * 128 + hcol];
        #pragma unroll
        for (int i = 0; i < 2; ++i) {
            int r = r2 * 2 + i;
            ya[i] += sh[r][d] * w;
            pa[i] += sc[r][d] * s;
        }
    }
    const float e1 = eta1p[0];
    #pragma unroll
    for (int i = 0; i < 2; ++i) {
        int r = r2 * 2 + i;
        float y = ya[i] + b1[hcol];
        sv[r][hcol] = y + e1 * tanhf(y) * pa[i];
    }
    __syncthreads();

    // LN(128) + gelu + c2: wave per row
    {
        int r = wv;
        float v0 = sv[r][lane];
        float v1 = sv[r][lane + 64];
        float s = v0 + v1, sq = v0 * v0 + v1 * v1;
        #pragma unroll
        for (int o = 32; o; o >>= 1) { s += __shfl_xor(s, o); sq += __shfl_xor(sq, o); }
        float mu = s * (1.f / 128.f);
        float var = sq * (1.f / 128.f) - mu * mu;
        float rs = rsqrtf(var + 1e-5f);
        float u0 = (v0 - mu) * rs * g1[lane] + be1[lane];
        float u1 = (v1 - mu) * rs * g1[lane + 64] + be1[lane + 64];
        float ge0 = gelu_f(u0);
        float ge1 = gelu_f(u1);
        float gsq = ge0 * ge0 + ge1 * ge1;
        #pragma unroll
        for (int o = 32; o; o >>= 1) gsq += __shfl_xor(gsq, o);
        float inv = 1.f / (sqrtf(gsq) + 1e-8f);
        sh2[r][lane] = ge0; sh2[r][lane + 64] = ge1;
        sc2[r][lane] = ge0 * ge0 * inv; sc2[r][lane + 64] = ge1 * ge1 * inv;
    }
    __syncthreads();

    // ---- layer 2: 64 outputs x 4 rows; one item per thread ----
    const int h2c = t & 63;
    const int r4 = t >> 6;           // 0..3
    float yb = 0.f, pb = 0.f;
    for (int d = 0; d < 128; ++d) {
        yb += sh2[r4][d] * W2T[d * 64 + h2c];
        pb += sc2[r4][d] * S2T[d * 64 + h2c];
    }
    {
        const float e2 = eta2p[0];
        float y = yb + b2[h2c];
        sv2[r4][h2c] = y + e2 * tanhf(y) * pb;
    }
    __syncthreads();

    // LN(64) + gelu + head: wave per row
    {
        int r = wv;
        float v0 = sv2[r][lane];
        float s = v0, sq = v0 * v0;
        #pragma unroll
        for (int o = 32; o; o >>= 1) { s += __shfl_xor(s, o); sq += __shfl_xor(sq, o); }
        float mu = s * (1.f / 64.f);
        float var = sq * (1.f / 64.f) - mu * mu;
        float rs = rsqrtf(var + 1e-5f);
        float u = (v0 - mu) * rs * g2[lane] + be2[lane];
        float g = gelu_f(u);
        float hc = g * hw[lane];
        #pragma unroll
        for (int o = 32; o; o >>= 1) hc += __shfl_xor(hc, o);
        if (lane == 0) out[b0 + r] = hc + hbod[0];
    }
}

// ---------------------------------------------------------------------------
extern "C" void kernel_launch(void* const* d_in, const int* in_sizes, int n_in,
                              void* d_out, int out_size, void* d_ws, size_t ws_size,
                              hipStream_t stream)
{
    const float* x    = (const float*)d_in[0];
    const float* W0   = (const float*)d_in[1];
    const float* A0   = (const float*)d_in[2];
    const float* b0   = (const float*)d_in[3];
    const float* eta0 = (const float*)d_in[4];
    const float* g0   = (const float*)d_in[5];
    const float* be0  = (const float*)d_in[6];
    const float* W1   = (const float*)d_in[7];
    const float* A1   = (const float*)d_in[8];
    const float* b1   = (const float*)d_in[9];
    const float* eta1 = (const float*)d_in[10];
    const float* g1   = (const float*)d_in[11];
    const float* be1  = (const float*)d_in[12];
    const float* W2   = (const float*)d_in[13];
    const float* A2   = (const float*)d_in[14];
    const float* b2   = (const float*)d_in[15];
    const float* eta2 = (const float*)d_in[16];
    const float* g2   = (const float*)d_in[17];
    const float* be2  = (const float*)d_in[18];
    const float* hw   = (const float*)d_in[19];
    const float* hbod = (const float*)d_in[20];
    float* out = (float*)d_out;

    char* w = (char*)d_ws;
    unsigned short* hb  = (unsigned short*)(w + 0);          // 20971520
    unsigned short* Wb0 = (unsigned short*)(w + 20971520);   // 5242880
    unsigned short* Sb0 = (unsigned short*)(w + 26214400);   // 5242880
    float* Py   = (float*)(w + 31457280);                    // 16777216
    float* Pp   = (float*)(w + 48234496);                    // 16777216
    float* W1T  = (float*)(w + 65011712);                    // 131072
    float* S1T  = (float*)(w + 65142784);                    // 131072
    float* W2T  = (float*)(w + 65273856);                    // 32768
    float* S2T  = (float*)(w + 65306624);                    // 32768
    float* hnm  = (float*)(w + 65339392);                    // 4096
    // total = 65343488 bytes

    hipLaunchKernelGGL(fft_prep_kernel, dim3(3804), dim3(512), 0, stream,
                       x, hb, hnm, W0, A0, Wb0, Sb0, W1, A1, W2, A2, W1T, S1T, W2T, S2T);
    hipLaunchKernelGGL(gemm0_kernel, dim3(8, 4, 16), dim3(256), 0, stream, hb, Wb0, Sb0, Py, Pp);
    hipLaunchKernelGGL(combine_tail_kernel, dim3(256), dim3(256), 0, stream, Py, Pp, hnm,
                       b0, eta0, g0, be0, W1T, S1T, b1, eta1, g1, be1,
                       W2T, S2T, b2, eta2, g2, be2, hw, hbod, out);
}